// Round 15
// baseline (70.429 us; speedup 1.0000x reference)
//
#include <hip/hip_runtime.h>
#include <hip/hip_fp16.h>

#define BB_ 8
#define VV_ 5023
#define FF_ 9976
#define HH_ 512
#define K_ADJ 32

static constexpr long long OUT_UV   = 0;                                   // uvcoords_images (B,3,H,H)
static constexpr long long OUT_POS  = OUT_UV   + (long long)BB_*3*HH_*HH_; // pos_mask        (B,1,H,H)
static constexpr long long OUT_GRID = OUT_POS  + (long long)BB_*HH_*HH_;   // grid            (B,H,H,2)
static constexpr long long OUT_N    = OUT_GRID + (long long)BB_*HH_*HH_*2; // normals         (B,V,3)
static constexpr long long OUT_NIMG = OUT_N    + (long long)BB_*VV_*3;     // normal_images   (B,3,H,H)
static constexpr long long OUT_TN   = OUT_NIMG + (long long)BB_*3*HH_*HH_; // t_normals       (B,V,3)

typedef float __attribute__((ext_vector_type(4))) f4;
typedef int   __attribute__((ext_vector_type(4))) i4;

__device__ inline unsigned short h16(float x) {
    __half h = __float2half_rn(x);
    return *(unsigned short*)&h;
}
__device__ inline unsigned int pack2u(float a, float b) {   // low = a
    return (unsigned int)h16(a) | ((unsigned int)h16(b) << 16);
}
__device__ inline float pack_h2(float a, float b) {
    union { float f; unsigned int u; } w;
    w.u = pack2u(a, b);
    return w.f;
}
__device__ inline float2 unpack_h2(float w) {
    union { float f; __half2 h; } u; u.f = w;
    return __half22float2(u.h);
}

// Record per (b,f): one 64-B line, ALL producer stores dword-or-wider aligned.
//   byte  0: tnz_a f32   [gather m1 k0]      byte  4: tnz_b   [m1 k1]
//   byte  8: tnz_c       [m1 k2]             byte 12: pack(uv8,0)  [facenorm]
//   byte 16: pack(nax,nay) 20: pack(naz,0)   [gather m0 k0, one float2]
//   byte 24: pack(nbx,nby) 28: pack(nbz,0)   [k1]
//   byte 32: pack(ncx,ncy) 36: pack(ncz,0)   [k2]
//   byte 40,44: pad (never read)
//   byte 48-63: uv01,uv23,uv45,uv67 halves   [facenorm, one float4]
// Every consumed byte written every call; byte-disjoint -> no races.

// ---------------------------------------------------------------------------
// K1: one face normal per (b, mesh, f); m==0 threads also write uv fields of
// rec[b*F+f]; bm==0 threads build corner-encoded adjacency (e = f*4 + k).
// All three reference scatter-adds equal cross(v1-v0, v2-v0); z+10 applied
// before differencing (matches ref rounding).
// ---------------------------------------------------------------------------
__global__ __launch_bounds__(64) void facenorm5_k(const float* __restrict__ verts,
                                                  const float* __restrict__ tverts,
                                                  const int*   __restrict__ faces,
                                                  const float* __restrict__ uvc,
                                                  float4* __restrict__ fnorm,
                                                  char*   __restrict__ rec,
                                                  int*    __restrict__ cnt,
                                                  int*    __restrict__ adj) {
    int t = blockIdx.x * 64 + threadIdx.x;
    if (t >= BB_ * 2 * FF_) return;
    int bm = t / FF_;                 // b*2 + m
    int f  = t - bm * FF_;
    int m  = bm & 1;
    int b  = bm >> 1;

    int i0 = faces[f*3+0], i1 = faces[f*3+1], i2 = faces[f*3+2];

    const float* vb = (m ? tverts : verts) + (long long)b * VV_ * 3;
    const float zoff = m ? 10.0f : 0.0f;
    float v0x = vb[i0*3+0], v0y = vb[i0*3+1], v0z = vb[i0*3+2] + zoff;
    float v1x = vb[i1*3+0], v1y = vb[i1*3+1], v1z = vb[i1*3+2] + zoff;
    float v2x = vb[i2*3+0], v2y = vb[i2*3+1], v2z = vb[i2*3+2] + zoff;
    float ax = v1x - v0x, ay = v1y - v0y, az = v1z - v0z;
    float bx = v2x - v0x, by = v2y - v0y, bz = v2z - v0z;
    fnorm[(long long)t] = make_float4(ay*bz - az*by, az*bx - ax*bz, ax*by - ay*bx, 0.f);

    if (m == 0) {
        const float* u = uvc + (long long)f * 9;
        float r0 = u[0]*0.5f+0.5f, r1 = u[1]*0.5f+0.5f, r2 = u[2]*0.5f+0.5f;
        float r3 = u[3]*0.5f+0.5f, r4 = u[4]*0.5f+0.5f, r5 = u[5]*0.5f+0.5f;
        float r6 = u[6]*0.5f+0.5f, r7 = u[7]*0.5f+0.5f, r8 = u[8]*0.5f+0.5f;
        char* rb = rec + ((long long)b * FF_ + f) * 64;
        *(float4*)(rb + 48) = make_float4(pack_h2(r0,r1), pack_h2(r2,r3),
                                          pack_h2(r4,r5), pack_h2(r6,r7));
        *(float*)(rb + 12)  = pack_h2(r8, 0.f);
    }

    if (bm == 0) {
        int s0 = atomicAdd(&cnt[i0], 1); if (s0 < K_ADJ) adj[i0*K_ADJ + s0] = f*4 + 0;
        int s1 = atomicAdd(&cnt[i1], 1); if (s1 < K_ADJ) adj[i1*K_ADJ + s1] = f*4 + 1;
        int s2 = atomicAdd(&cnt[i2], 1); if (s2 < K_ADJ) adj[i2*K_ADJ + s2] = f*4 + 2;
    }
}

// ---------------------------------------------------------------------------
// K2: gather per (b, mesh, v): sum adjacent face normals, normalize, write
// normals / t_normals outputs, then scatter record fields into every adjacent
// face's rec line. No local array (adj row re-read, L1-hot); all stores
// dword-or-wider aligned.
// ---------------------------------------------------------------------------
__global__ __launch_bounds__(64) void gather5_k(const int* __restrict__ cnt,
                                                const int* __restrict__ adj,
                                                const float4* __restrict__ fnorm,
                                                float* __restrict__ outN,
                                                float* __restrict__ outTN,
                                                char*  __restrict__ rec) {
    int t = blockIdx.x * 64 + threadIdx.x;
    if (t >= BB_ * 2 * VV_) return;
    int bm = t / VV_;                 // b*2 + m
    int v  = t - bm * VV_;
    int m  = bm & 1;
    int b  = bm >> 1;

    int deg = min(cnt[v], K_ADJ);
    const float4* fb = fnorm + (long long)bm * FF_;
    const int* arow = adj + v * K_ADJ;
    float x = 0.f, y = 0.f, z = 0.f;
    for (int j = 0; j < deg; ++j) {
        float4 a = fb[arow[j] >> 2];
        x += a.x; y += a.y; z += a.z;
    }
    float inv = 1.0f / fmaxf(sqrtf(x*x + y*y + z*z), 1e-6f);
    float nx = x * inv, ny = y * inv, nz = z * inv;

    long long idx = (long long)b * VV_ + v;
    char* rbase = rec + (long long)b * FF_ * 64;

    if (m == 0) {
        float* o = outN + idx * 3;
        o[0] = nx; o[1] = ny; o[2] = nz;
        float2 pkt = make_float2(pack_h2(nx, ny), pack_h2(nz, 0.f));
        for (int j = 0; j < deg; ++j) {
            int e = arow[j];
            int f = e >> 2, k = e & 3;
            *(float2*)(rbase + (long long)f * 64 + 16 + 8*k) = pkt;
        }
    } else {
        float* o = outTN + idx * 3;
        o[0] = nx; o[1] = ny; o[2] = nz;
        for (int j = 0; j < deg; ++j) {
            int e = arow[j];
            int f = e >> 2, k = e & 3;
            *(float*)(rbase + (long long)f * 64 + 4*k) = nz;   // tnz_k fp32
        }
    }
}

// ---------------------------------------------------------------------------
// Per-pixel shade: 4 dwordx4 loads from ONE 64-B line; miss pixels issue
// zero gather traffic.
// ---------------------------------------------------------------------------
__device__ __forceinline__ void shade(int pf, float w0, float w1, float w2,
                                      const float4* __restrict__ rec,
                                      float& uv0, float& uv1, float& uv2,
                                      float& n0, float& n1, float& n2, float& pm) {
    uv0 = uv1 = uv2 = n0 = n1 = n2 = pm = 0.0f;
    if (pf < 0) return;
    const float4* R = rec + (long long)pf * 4;
    float4 q0 = R[0], q1 = R[1], q2 = R[2], q3 = R[3];

    float  u8  = unpack_h2(q0.w).x;
    float2 na  = unpack_h2(q1.x); float naz = unpack_h2(q1.y).x;
    float2 nb  = unpack_h2(q1.z); float nbz = unpack_h2(q1.w).x;
    float2 nc  = unpack_h2(q2.x); float ncz = unpack_h2(q2.y).x;
    float2 u01 = unpack_h2(q3.x), u23 = unpack_h2(q3.y);
    float2 u45 = unpack_h2(q3.z), u67 = unpack_h2(q3.w);

    uv0 = w0*u01.x + w1*u23.y + w2*u67.x;
    uv1 = w0*u01.y + w1*u45.x + w2*u67.y;
    uv2 = w0*u23.x + w1*u45.y + w2*u8;
    n0  = w0*na.x + w1*nb.x + w2*nc.x;
    n1  = w0*na.y + w1*nb.y + w2*nc.y;
    n2  = w0*naz  + w1*nbz  + w2*ncz;
    float tnz = w0*q0.x + w1*q0.y + w2*q0.z;   // fp32: hard threshold
    pm = (tnz < -0.05f) ? 1.0f : 0.0f;
}

// ---------------------------------------------------------------------------
// K3: raster, 4 consecutive pixels/thread. Plain loads for streams (L3/L2
// resident), NT stores for write-once outputs.
// ---------------------------------------------------------------------------
__global__ __launch_bounds__(256) void raster6(const i4* __restrict__ p2f4,
                                               const f4* __restrict__ bary4,
                                               const float4* __restrict__ rec,
                                               float* __restrict__ out) {
    int t = blockIdx.x * blockDim.x + threadIdx.x;
    const int NQ = BB_ * HH_ * HH_ / 4;
    if (t >= NQ) return;
    int pix0 = t << 2;
    int b    = pix0 >> 18;               // H*H = 2^18
    int yx0  = pix0 & (HH_*HH_ - 1);

    i4 pf = p2f4[t];
    f4 B0 = bary4[(long long)t*3 + 0];
    f4 B1 = bary4[(long long)t*3 + 1];
    f4 B2 = bary4[(long long)t*3 + 2];

    float uv0a, uv1a, uv2a, n0a, n1a, n2a, pma;
    float uv0b, uv1b, uv2b, n0b, n1b, n2b, pmb;
    float uv0c, uv1c, uv2c, n0c, n1c, n2c, pmc;
    float uv0d, uv1d, uv2d, n0d, n1d, n2d, pmd;

    shade(pf.x, B0.x, B0.y, B0.z, rec, uv0a, uv1a, uv2a, n0a, n1a, n2a, pma);
    shade(pf.y, B0.w, B1.x, B1.y, rec, uv0b, uv1b, uv2b, n0b, n1b, n2b, pmb);
    shade(pf.z, B1.z, B1.w, B2.x, rec, uv0c, uv1c, uv2c, n0c, n1c, n2c, pmc);
    shade(pf.w, B2.y, B2.z, B2.w, rec, uv0d, uv1d, uv2d, n0d, n1d, n2d, pmd);

    const long long HW = (long long)HH_ * HH_;
    f4 vuv0 = {uv0a, uv0b, uv0c, uv0d};
    f4 vuv1 = {uv1a, uv1b, uv1c, uv1d};
    f4 vuv2 = {uv2a, uv2b, uv2c, uv2d};
    f4 vpos = {pma,  pmb,  pmc,  pmd};
    f4 vg0  = {uv0a, uv1a, uv0b, uv1b};
    f4 vg1  = {uv0c, uv1c, uv0d, uv1d};
    f4 vn0  = {n0a, n0b, n0c, n0d};
    f4 vn1  = {n1a, n1b, n1c, n1d};
    f4 vn2  = {n2a, n2b, n2c, n2d};

    __builtin_nontemporal_store(vuv0, (f4*)(out + OUT_UV  + ((long long)(b*3+0))*HW + yx0));
    __builtin_nontemporal_store(vuv1, (f4*)(out + OUT_UV  + ((long long)(b*3+1))*HW + yx0));
    __builtin_nontemporal_store(vuv2, (f4*)(out + OUT_UV  + ((long long)(b*3+2))*HW + yx0));
    __builtin_nontemporal_store(vpos, (f4*)(out + OUT_POS + (long long)b*HW + yx0));
    float* gbase = out + OUT_GRID + ((long long)b*HW + yx0)*2;
    __builtin_nontemporal_store(vg0, (f4*)(gbase + 0));
    __builtin_nontemporal_store(vg1, (f4*)(gbase + 4));
    __builtin_nontemporal_store(vn0, (f4*)(out + OUT_NIMG + ((long long)(b*3+0))*HW + yx0));
    __builtin_nontemporal_store(vn1, (f4*)(out + OUT_NIMG + ((long long)(b*3+1))*HW + yx0));
    __builtin_nontemporal_store(vn2, (f4*)(out + OUT_NIMG + ((long long)(b*3+2))*HW + yx0));
}

extern "C" void kernel_launch(void* const* d_in, const int* in_sizes, int n_in,
                              void* d_out, int out_size, void* d_ws, size_t ws_size,
                              hipStream_t stream) {
    const float* vertices  = (const float*)d_in[0];
    const float* tvertices = (const float*)d_in[1];
    const float* face_uvc  = (const float*)d_in[3];
    const float* bary      = (const float*)d_in[4];
    const int*   faces     = (const int*)d_in[5];
    const int*   p2f       = (const int*)d_in[6];

    float* out = (float*)d_out;

    // ws layout (64B-aligned first): rec | fnorm | cnt | adj
    char*   rec   = (char*)d_ws;                                 // B*F*64 bytes
    float4* fnorm = (float4*)(rec + (size_t)BB_ * FF_ * 64);     // B*2*F float4
    int*    cnt   = (int*)(fnorm + (size_t)BB_ * 2 * FF_);       // V
    int*    adj   = cnt + VV_;                                   // V*K_ADJ

    hipMemsetAsync(cnt, 0, (size_t)VV_ * sizeof(int), stream);

    {
        int n = BB_ * 2 * FF_;
        facenorm5_k<<<(n + 63) / 64, 64, 0, stream>>>(vertices, tvertices, faces,
                                                      face_uvc, fnorm, rec, cnt, adj);
    }
    {
        int n = BB_ * 2 * VV_;
        gather5_k<<<(n + 63) / 64, 64, 0, stream>>>(cnt, adj, fnorm,
                                                    out + OUT_N, out + OUT_TN, rec);
    }
    {
        int nq = BB_ * HH_ * HH_ / 4;
        raster6<<<(nq + 255) / 256, 256, 0, stream>>>((const i4*)p2f, (const f4*)bary,
                                                      (const float4*)rec, out);
    }
}

// Round 16
// 63.062 us; speedup vs baseline: 1.1168x; 1.1168x over previous
//
#include <hip/hip_runtime.h>
#include <hip/hip_fp16.h>

#define BB_ 8
#define VV_ 5023
#define FF_ 9976
#define HH_ 512
#define K_ADJ 32

static constexpr long long OUT_UV   = 0;                                   // uvcoords_images (B,3,H,H)
static constexpr long long OUT_POS  = OUT_UV   + (long long)BB_*3*HH_*HH_; // pos_mask        (B,1,H,H)
static constexpr long long OUT_GRID = OUT_POS  + (long long)BB_*HH_*HH_;   // grid            (B,H,H,2)
static constexpr long long OUT_N    = OUT_GRID + (long long)BB_*HH_*HH_*2; // normals         (B,V,3)
static constexpr long long OUT_NIMG = OUT_N    + (long long)BB_*VV_*3;     // normal_images   (B,3,H,H)
static constexpr long long OUT_TN   = OUT_NIMG + (long long)BB_*3*HH_*HH_; // t_normals       (B,V,3)

typedef float __attribute__((ext_vector_type(4))) f4;
typedef int   __attribute__((ext_vector_type(4))) i4;

__device__ inline unsigned short h16(float x) {
    __half h = __float2half_rn(x);
    return *(unsigned short*)&h;
}
__device__ inline unsigned int pack2u(float a, float b) {   // low = a
    return (unsigned int)h16(a) | ((unsigned int)h16(b) << 16);
}
__device__ inline float pack_h2(float a, float b) {
    union { float f; unsigned int u; } w;
    w.u = pack2u(a, b);
    return w.f;
}
__device__ inline float2 unpack_h2(float w) {
    union { float f; __half2 h; } u; u.f = w;
    return __half22float2(u.h);
}

// ---------------------------------------------------------------------------
// K1: one face normal per (b, mesh, f) -- 64-thread blocks (CU coverage).
// bm==0 threads also build the adjacency table (int atomics; K=32 >> max deg).
// All three reference scatter-adds equal cross(v1-v0, v2-v0); z+10 applied
// before differencing (matches ref rounding).
// ---------------------------------------------------------------------------
__global__ __launch_bounds__(64) void facenorm3_k(const float* __restrict__ verts,
                                                  const float* __restrict__ tverts,
                                                  const int*   __restrict__ faces,
                                                  float4* __restrict__ fnorm,
                                                  int*    __restrict__ cnt,
                                                  int*    __restrict__ adj) {
    int t = blockIdx.x * 64 + threadIdx.x;
    if (t >= BB_ * 2 * FF_) return;
    int bm = t / FF_;                 // b*2 + m
    int f  = t - bm * FF_;
    int m  = bm & 1;
    int b  = bm >> 1;

    int i0 = faces[f*3+0], i1 = faces[f*3+1], i2 = faces[f*3+2];

    const float* vb = (m ? tverts : verts) + (long long)b * VV_ * 3;
    const float zoff = m ? 10.0f : 0.0f;
    float v0x = vb[i0*3+0], v0y = vb[i0*3+1], v0z = vb[i0*3+2] + zoff;
    float v1x = vb[i1*3+0], v1y = vb[i1*3+1], v1z = vb[i1*3+2] + zoff;
    float v2x = vb[i2*3+0], v2y = vb[i2*3+1], v2z = vb[i2*3+2] + zoff;
    float ax = v1x - v0x, ay = v1y - v0y, az = v1z - v0z;
    float bx = v2x - v0x, by = v2y - v0y, bz = v2z - v0z;
    fnorm[(long long)t] = make_float4(ay*bz - az*by, az*bx - ax*bz, ax*by - ay*bx, 0.f);

    if (bm == 0) {
        int s0 = atomicAdd(&cnt[i0], 1); if (s0 < K_ADJ) adj[i0*K_ADJ + s0] = f;
        int s1 = atomicAdd(&cnt[i1], 1); if (s1 < K_ADJ) adj[i1*K_ADJ + s1] = f;
        int s2 = atomicAdd(&cnt[i2], 1); if (s2 < K_ADJ) adj[i2*K_ADJ + s2] = f;
    }
}

// ---------------------------------------------------------------------------
// K2: gather per (b, mesh, v) -- 64-thread blocks. m==0 writes normals output
// + nbuf.xyz; m==1 writes t_normals output + nbuf.w (=tnz). Disjoint bytes of
// the same float4 -> no race.
// ---------------------------------------------------------------------------
__global__ __launch_bounds__(64) void gather3_k(const int* __restrict__ cnt,
                                                const int* __restrict__ adj,
                                                const float4* __restrict__ fnorm,
                                                float* __restrict__ outN,
                                                float* __restrict__ outTN,
                                                float4* __restrict__ nbuf) {
    int t = blockIdx.x * 64 + threadIdx.x;
    if (t >= BB_ * 2 * VV_) return;
    int bm = t / VV_;                 // b*2 + m
    int v  = t - bm * VV_;
    int m  = bm & 1;
    int b  = bm >> 1;

    int deg = min(cnt[v], K_ADJ);
    const float4* fb = fnorm + (long long)bm * FF_;
    float x = 0.f, y = 0.f, z = 0.f;
    for (int j = 0; j < deg; ++j) {
        int f = adj[v*K_ADJ + j];
        float4 a = fb[f];
        x += a.x; y += a.y; z += a.z;
    }
    float inv = 1.0f / fmaxf(sqrtf(x*x + y*y + z*z), 1e-6f);
    float nx = x * inv, ny = y * inv, nz = z * inv;

    long long idx = (long long)b * VV_ + v;
    float* nb = (float*)(nbuf + idx);
    if (m == 0) {
        float* o = outN + idx * 3;
        o[0] = nx; o[1] = ny; o[2] = nz;
        nb[0] = nx; nb[1] = ny; nb[2] = nz;
    } else {
        float* o = outTN + idx * 3;
        o[0] = nx; o[1] = ny; o[2] = nz;
        nb[3] = nz;                   // tnz (fp32: hard-threshold path)
    }
}

// ---------------------------------------------------------------------------
// K3: ONE 64-B record per (b,f) from 3 aligned float4 nbuf reads + uvc.
//   q0: tnz0..2 fp32 (hard-threshold path), pack(uv8, ncz)
//   q1: uv0..7 halves (pre-scaled);  q2: nax..ncy halves;  q3: pad.
// ---------------------------------------------------------------------------
__global__ __launch_bounds__(64) void build_rec64(const int*    __restrict__ faces,
                                                  const float*  __restrict__ uvc,
                                                  const float4* __restrict__ nbuf,
                                                  float4* __restrict__ rec) {
    int t = blockIdx.x * 64 + threadIdx.x;
    if (t >= BB_ * FF_) return;
    int b = t / FF_;
    int f = t - b * FF_;
    int ia = faces[f*3+0], ib = faces[f*3+1], ic = faces[f*3+2];

    const float4* nb = nbuf + (long long)b * VV_;
    float4 A = nb[ia], Bv = nb[ib], C = nb[ic];

    const float* u = uvc + (long long)f * 9;
    float r0 = u[0]*0.5f+0.5f, r1 = u[1]*0.5f+0.5f, r2 = u[2]*0.5f+0.5f;
    float r3 = u[3]*0.5f+0.5f, r4 = u[4]*0.5f+0.5f, r5 = u[5]*0.5f+0.5f;
    float r6 = u[6]*0.5f+0.5f, r7 = u[7]*0.5f+0.5f, r8 = u[8]*0.5f+0.5f;

    float4* o = rec + (long long)t * 4;
    o[0] = make_float4(A.w, Bv.w, C.w, pack_h2(r8, C.z));
    o[1] = make_float4(pack_h2(r0,r1), pack_h2(r2,r3), pack_h2(r4,r5), pack_h2(r6,r7));
    o[2] = make_float4(pack_h2(A.x,A.y), pack_h2(A.z,Bv.x), pack_h2(Bv.y,Bv.z), pack_h2(C.x,C.y));
}

// ---------------------------------------------------------------------------
// Per-pixel shade: 3 dwordx4 loads from ONE 64-B line; miss pixels issue
// zero gather traffic. (Proven round-10/13 layout.)
// ---------------------------------------------------------------------------
__device__ __forceinline__ void shade(int pf, float w0, float w1, float w2,
                                      const float4* __restrict__ rec,
                                      float& uv0, float& uv1, float& uv2,
                                      float& n0, float& n1, float& n2, float& pm) {
    uv0 = uv1 = uv2 = n0 = n1 = n2 = pm = 0.0f;
    if (pf < 0) return;
    const float4* R = rec + (long long)pf * 4;
    float4 q0 = R[0], q1 = R[1], q2 = R[2];

    float2 u8c = unpack_h2(q0.w);     // (uv8, ncz)
    float2 u01 = unpack_h2(q1.x), u23 = unpack_h2(q1.y);
    float2 u45 = unpack_h2(q1.z), u67 = unpack_h2(q1.w);
    float2 m01 = unpack_h2(q2.x), m23 = unpack_h2(q2.y);
    float2 m45 = unpack_h2(q2.z), m67 = unpack_h2(q2.w);

    uv0 = w0*u01.x + w1*u23.y + w2*u67.x;
    uv1 = w0*u01.y + w1*u45.x + w2*u67.y;
    uv2 = w0*u23.x + w1*u45.y + w2*u8c.x;
    n0  = w0*m01.x + w1*m23.y + w2*m67.x;
    n1  = w0*m01.y + w1*m45.x + w2*m67.y;
    n2  = w0*m23.x + w1*m45.y + w2*u8c.y;
    float tnz = w0*q0.x + w1*q0.y + w2*q0.z;   // fp32: hard threshold
    pm = (tnz < -0.05f) ? 1.0f : 0.0f;
}

// ---------------------------------------------------------------------------
// K4: raster, 4 consecutive pixels/thread, XCD-AWARE BLOCK SWIZZLE.
// B == 8 == #XCDs: swz = (bid%8)*256 + bid/8 (bijective, 2048 = 8*256) puts
// all 256 blocks of batch x on XCD x -> per-XCD L2 only needs that batch's
// 640 KB rec slice -> rec gathers become L2 hits (~200cy) instead of HBM
// misses (~900cy). Plain loads for streams, NT stores for outputs.
// ---------------------------------------------------------------------------
__global__ __launch_bounds__(256) void raster6(const i4* __restrict__ p2f4,
                                               const f4* __restrict__ bary4,
                                               const float4* __restrict__ rec,
                                               float* __restrict__ out) {
    const int NQ = BB_ * HH_ * HH_ / 4;          // 524288 quads, 2048 blocks
    int swzb = ((blockIdx.x & 7) << 8) + (blockIdx.x >> 3);   // bijective
    int t = swzb * blockDim.x + threadIdx.x;
    if (t >= NQ) return;
    int pix0 = t << 2;
    int b    = pix0 >> 18;               // H*H = 2^18
    int yx0  = pix0 & (HH_*HH_ - 1);

    i4 pf = p2f4[t];
    f4 B0 = bary4[(long long)t*3 + 0];
    f4 B1 = bary4[(long long)t*3 + 1];
    f4 B2 = bary4[(long long)t*3 + 2];

    float uv0a, uv1a, uv2a, n0a, n1a, n2a, pma;
    float uv0b, uv1b, uv2b, n0b, n1b, n2b, pmb;
    float uv0c, uv1c, uv2c, n0c, n1c, n2c, pmc;
    float uv0d, uv1d, uv2d, n0d, n1d, n2d, pmd;

    shade(pf.x, B0.x, B0.y, B0.z, rec, uv0a, uv1a, uv2a, n0a, n1a, n2a, pma);
    shade(pf.y, B0.w, B1.x, B1.y, rec, uv0b, uv1b, uv2b, n0b, n1b, n2b, pmb);
    shade(pf.z, B1.z, B1.w, B2.x, rec, uv0c, uv1c, uv2c, n0c, n1c, n2c, pmc);
    shade(pf.w, B2.y, B2.z, B2.w, rec, uv0d, uv1d, uv2d, n0d, n1d, n2d, pmd);

    const long long HW = (long long)HH_ * HH_;
    f4 vuv0 = {uv0a, uv0b, uv0c, uv0d};
    f4 vuv1 = {uv1a, uv1b, uv1c, uv1d};
    f4 vuv2 = {uv2a, uv2b, uv2c, uv2d};
    f4 vpos = {pma,  pmb,  pmc,  pmd};
    f4 vg0  = {uv0a, uv1a, uv0b, uv1b};
    f4 vg1  = {uv0c, uv1c, uv0d, uv1d};
    f4 vn0  = {n0a, n0b, n0c, n0d};
    f4 vn1  = {n1a, n1b, n1c, n1d};
    f4 vn2  = {n2a, n2b, n2c, n2d};

    __builtin_nontemporal_store(vuv0, (f4*)(out + OUT_UV  + ((long long)(b*3+0))*HW + yx0));
    __builtin_nontemporal_store(vuv1, (f4*)(out + OUT_UV  + ((long long)(b*3+1))*HW + yx0));
    __builtin_nontemporal_store(vuv2, (f4*)(out + OUT_UV  + ((long long)(b*3+2))*HW + yx0));
    __builtin_nontemporal_store(vpos, (f4*)(out + OUT_POS + (long long)b*HW + yx0));
    float* gbase = out + OUT_GRID + ((long long)b*HW + yx0)*2;
    __builtin_nontemporal_store(vg0, (f4*)(gbase + 0));
    __builtin_nontemporal_store(vg1, (f4*)(gbase + 4));
    __builtin_nontemporal_store(vn0, (f4*)(out + OUT_NIMG + ((long long)(b*3+0))*HW + yx0));
    __builtin_nontemporal_store(vn1, (f4*)(out + OUT_NIMG + ((long long)(b*3+1))*HW + yx0));
    __builtin_nontemporal_store(vn2, (f4*)(out + OUT_NIMG + ((long long)(b*3+2))*HW + yx0));
}

extern "C" void kernel_launch(void* const* d_in, const int* in_sizes, int n_in,
                              void* d_out, int out_size, void* d_ws, size_t ws_size,
                              hipStream_t stream) {
    const float* vertices  = (const float*)d_in[0];
    const float* tvertices = (const float*)d_in[1];
    const float* face_uvc  = (const float*)d_in[3];
    const float* bary      = (const float*)d_in[4];
    const int*   faces     = (const int*)d_in[5];
    const int*   p2f       = (const int*)d_in[6];

    float* out = (float*)d_out;

    // ws layout (16B-aligned first): rec | fnorm | nbuf | cnt | adj
    float4* rec   = (float4*)d_ws;                               // B*F*4 float4
    float4* fnorm = rec + (size_t)BB_ * FF_ * 4;                 // B*2*F float4
    float4* nbuf  = fnorm + (size_t)BB_ * 2 * FF_;               // B*V float4
    int*    cnt   = (int*)(nbuf + (size_t)BB_ * VV_);            // V
    int*    adj   = cnt + VV_;                                   // V*K_ADJ

    hipMemsetAsync(cnt, 0, (size_t)VV_ * sizeof(int), stream);

    {
        int n = BB_ * 2 * FF_;
        facenorm3_k<<<(n + 63) / 64, 64, 0, stream>>>(vertices, tvertices, faces,
                                                      fnorm, cnt, adj);
    }
    {
        int n = BB_ * 2 * VV_;
        gather3_k<<<(n + 63) / 64, 64, 0, stream>>>(cnt, adj, fnorm,
                                                    out + OUT_N, out + OUT_TN, nbuf);
    }
    {
        int n = BB_ * FF_;
        build_rec64<<<(n + 63) / 64, 64, 0, stream>>>(faces, face_uvc, nbuf, rec);
    }
    {
        int nq = BB_ * HH_ * HH_ / 4;
        raster6<<<(nq + 255) / 256, 256, 0, stream>>>((const i4*)p2f, (const f4*)bary,
                                                      rec, out);
    }
}